// Round 1
// baseline (48.127 us; speedup 1.0000x reference)
//
#include <hip/hip_runtime.h>

// Complex BatchNorm (training-mode whitening) for z:[B=32, N=C*H*W, 2] fp32.
// One thread per position n: loads all 32 batch samples into registers,
// computes mean + 2x2 covariance, closed-form inverse-sqrt, fuses gamma,
// writes whitened+affine output. Single pass over HBM (read 128MiB + write
// 128MiB).

constexpr int BATCH = 32;

__global__ __launch_bounds__(256) void cbn_kernel(
    const float* __restrict__ z,
    const float* __restrict__ gamma,
    const float* __restrict__ beta,
    float* __restrict__ out,
    int N)
{
    int n = blockIdx.x * blockDim.x + threadIdx.x;
    if (n >= N) return;

    const float2* __restrict__ zp = (const float2*)z;
    float2* __restrict__ op = (float2*)out;

    // Load all 32 batch samples for this position (64 VGPRs of data).
    float2 v[BATCH];
#pragma unroll
    for (int b = 0; b < BATCH; ++b) {
        v[b] = zp[(size_t)b * N + n];
    }

    // Mean over batch.
    float mx = 0.f, my = 0.f;
#pragma unroll
    for (int b = 0; b < BATCH; ++b) { mx += v[b].x; my += v[b].y; }
    mx *= (1.0f / BATCH);
    my *= (1.0f / BATCH);

    // Unbiased 2x2 covariance.
    float sxx = 0.f, sxy = 0.f, syy = 0.f;
#pragma unroll
    for (int b = 0; b < BATCH; ++b) {
        float dx = v[b].x - mx;
        float dy = v[b].y - my;
        sxx += dx * dx;
        sxy += dx * dy;
        syy += dy * dy;
    }
    const float inv = 1.0f / (BATCH - 1);
    sxx *= inv; sxy *= inv; syy *= inv;

    // Closed-form "(sigma + s*I)/t" as in the reference.
    float trace = sxx + syy;
    float det = sxx * syy - sxy * sxy;
    float s = sqrtf(det);
    float t = sqrtf(trace + 2.0f * s);
    float rt = 1.0f / t;

    float a00 = (sxx + s) * rt;
    float a01 = sxy * rt;          // symmetric: a10 == a01
    float a11 = (syy + s) * rt;

    // Fuse gamma into the whitening matrix: C = gamma * m_inv.
    float g00 = gamma[0], g01 = gamma[1], g10 = gamma[2], g11 = gamma[3];
    float b0 = beta[0], b1 = beta[1];

    float c00 = g00 * a00 + g01 * a01;
    float c01 = g00 * a01 + g01 * a11;
    float c10 = g10 * a00 + g11 * a01;
    float c11 = g10 * a01 + g11 * a11;

    // Apply and store.
#pragma unroll
    for (int b = 0; b < BATCH; ++b) {
        float dx = v[b].x - mx;
        float dy = v[b].y - my;
        float2 o;
        o.x = c00 * dx + c01 * dy + b0;
        o.y = c10 * dx + c11 * dy + b1;
        op[(size_t)b * N + n] = o;
    }
}

extern "C" void kernel_launch(void* const* d_in, const int* in_sizes, int n_in,
                              void* d_out, int out_size, void* d_ws, size_t ws_size,
                              hipStream_t stream) {
    const float* z     = (const float*)d_in[0];
    const float* gamma = (const float*)d_in[1];
    const float* beta  = (const float*)d_in[2];
    float* out = (float*)d_out;

    // in_sizes[0] = B * N * 2 = 32 * N * 2
    int N = in_sizes[0] / (BATCH * 2);

    dim3 block(256);
    dim3 grid((N + block.x - 1) / block.x);
    hipLaunchKernelGGL(cbn_kernel, grid, block, 0, stream, z, gamma, beta, out, N);
}